// Round 6
// baseline (366.226 us; speedup 1.0000x reference)
//
#include <hip/hip_runtime.h>
#include <hip/hip_cooperative_groups.h>
#include <math.h>

namespace cg = cooperative_groups;

// Problem constants
#define NQ   65536
#define H    32
#define IN   64
#define OUTC 64
#define K    15
#define QB   16          // queries per tile
#define NTILE 4096
#define INV_EXT (1.0f / 0.048f)

// d_ws layout (bytes)
#define OFF_PSUM  131072                       // Bfrag region: 65536 shorts = 128 KB exact
#define OFF_SCSH  (OFF_PSUM + 2097152)         // 128 floats (gsum: s[64], s2[64])
#define OFF_XBF   (OFF_SCSH + 1024)            // x in bf16: 8 MB
#define NEED_BF16 (OFF_XBF + (size_t)NQ * IN * 2)

typedef __attribute__((ext_vector_type(8))) short short8;
typedef __attribute__((ext_vector_type(4))) short short4v;
typedef __attribute__((ext_vector_type(4))) float float4v;

static __device__ __forceinline__ unsigned short f2bf(float f) {
    return (unsigned short)((__float_as_uint(f) + 0x8000u) >> 16);
}
static __device__ __forceinline__ unsigned pk2(float a, float b) {
    return (__float_as_uint(a) + 0x8000u) >> 16 |
           ((__float_as_uint(b) + 0x8000u) & 0xFFFF0000u);
}

// ===========================================================================
// FUSED cooperative kernel (R18). Rationale: across R0-R5 the end-to-end time
// was always kpconv + ~86 us -- the 3 inter-kernel gaps dominate (aux kernels'
// real work is ~15 us). Phases:
//   0: W repack + x->bf16 + zero stat accumulator      -> grid.sync
//   1: grid-stride over 4096 tiles (R5 body verbatim); out written raw;
//      per-channel s/s2 accumulated in regs, 1 atomicAdd/channel/block
//   2: compute BN scale/shift from global sums, apply BN+LeakyReLU in place
// ===========================================================================
template<bool BFX>
__global__ __launch_bounds__(256, 4) void kpconv_fused(
    const float* __restrict__ x, unsigned short* __restrict__ xbf,
    const float* __restrict__ qp, const float* __restrict__ sp,
    const int* __restrict__ inds, const float* __restrict__ kp,
    short* __restrict__ Bfrag, const float* __restrict__ W,
    const float* __restrict__ gamma, const float* __restrict__ beta,
    float* __restrict__ out, float* __restrict__ gsum)
{
    __shared__ __align__(16) short lds[16384];            // 32768 B exact
    short* xn  = lds;                                     // 4 waves x 2112 shorts, staggered
    short* wT2 = lds + 8448;                              // [16 qg][512] tr-layout

    const int tid  = threadIdx.x;
    const int lane = tid & 63;
    const int wv   = tid >> 6;
    const int quad = lane >> 4;
    const int ml   = lane & 15;
    const int q8   = lane >> 3;                           // neighbor slot 0..7 (contiguous lanes)
    const int m8   = lane & 7;                            // feat octet 0..7
    const int G    = gridDim.x;

    // ---------------- Phase 0: prep ----------------
    if (blockIdx.x < 256) {                               // W repack (128 KB)
        const int t2  = blockIdx.x * 256 + tid;           // 0..65535
        const int j   = t2 & 7;
        const int ln  = (t2 >> 3) & 63;
        const int tt  = (t2 >> 9) & 31;
        const int wvq = t2 >> 14;
        const int kp2 = tt * 32 + (ln >> 4) * 8 + j;      // k' = i*16 + kq
        const int kq  = kp2 & 15;
        const int ii  = kp2 >> 4;
        const int oo  = wvq * 16 + (ln & 15);
        const float val = (kq < K) ? W[(kq * 64 + ii) * 64 + oo] : 0.0f;
        Bfrag[t2] = (short)f2bf(val);
    }
    if (BFX) {                                            // x -> bf16, grid-stride
        for (unsigned t = blockIdx.x * 256u + tid; t < 1048576u; t += (unsigned)G * 256u) {
            const float4 v = ((const float4*)x)[t];
            uint2 p; p.x = pk2(v.x, v.y); p.y = pk2(v.z, v.w);
            ((uint2*)xbf)[t] = p;
        }
    }
    if (blockIdx.x == 0 && tid < 128) gsum[tid] = 0.0f;
    __threadfence();
    cg::this_grid().sync();

    // ---------------- Phase 1: tiles ----------------
    short* xn_own = xn + wv * 2112;                       // wave-private tr buffer (4224 B)
    const unsigned ldsb = (unsigned)(size_t)(&lds[0]);
    const unsigned xnb  = ldsb + (unsigned)(wv * 4224 + lane * 8);
    const unsigned wtb  = ldsb + 16896u + (unsigned)(wv * 4096 + lane * 8);
    const int hbase_q8  = q8;                             // neighbor slot
    const int Eb = (m8 >> 1) * 528 + ((q8 >> 2) & 1) * 256 + (q8 & 3) * 16 + (m8 & 1) * 8;

    float s_tot = 0.0f, s2_tot = 0.0f;

    for (int tile = blockIdx.x; tile < NTILE; tile += G) {
        const int q0 = tile * QB;

        // ---- Prefetch ALL 4 queries' gathers: 16B/lane, coalesced ----
        short8  xv[4][4];
        float4v xf[4][4][2];
#pragma unroll
        for (int qi = 0; qi < 4; ++qi) {
            const int ibase = (q0 + wv * 4 + qi) * H;
#pragma unroll
            for (int j = 0; j < 4; ++j) {
                const int id = inds[ibase + j * 8 + hbase_q8];
                if (BFX) {
                    xv[qi][j] = *(const short8*)((const short*)xbf + id * IN + m8 * 8);
                } else {
                    xf[qi][j][0] = *(const float4v*)(x + id * IN + m8 * 8);
                    xf[qi][j][1] = *(const float4v*)(x + id * IN + m8 * 8 + 4);
                }
            }
        }

        // ---- Stage A: influence weights -> wT2 tr-layout ----
#pragma unroll
        for (int rep = 0; rep < 2; ++rep) {
            const int p  = lane + rep * 64;      // 0..127
            const int qi = p >> 5, h = p & 31;
            const int qg = wv * 4 + qi;
            const int n  = q0 + qg;
            const int id = inds[n * H + h];
            const float dx = sp[id * 3 + 0] - qp[n * 3 + 0];
            const float dy = sp[id * 3 + 1] - qp[n * 3 + 1];
            const float dz = sp[id * 3 + 2] - qp[n * 3 + 2];
            short8 w0, w1;
#pragma unroll
            for (int k = 0; k < K; ++k) {
                const float ex = dx - kp[k * 3 + 0];
                const float ey = dy - kp[k * 3 + 1];
                const float ez = dz - kp[k * 3 + 2];
                const float sq = ex * ex + ey * ey + ez * ez;
                float wval = 1.0f - __builtin_amdgcn_sqrtf(sq) * INV_EXT;
                wval = wval > 0.0f ? wval : 0.0f;
                if (k < 8) w0[k]     = (short)f2bf(wval);
                else       w1[k - 8] = (short)f2bf(wval);
            }
            w1[7] = 0;                           // kq = 15 zero column
            short* dst = wT2 + qg * 512 + ((h >> 2) & 1) * 256 + (h >> 3) * 64 + (h & 3) * 16;
            *(short8*)dst       = w0;
            *(short8*)(dst + 8) = w1;
        }
        // no barrier: wT2 rows qg in [4wv,4wv+4) are read only by this wave

        // Pin 12/16 prefetched values live (input-only asm uses -> no sink)
#pragma unroll
        for (int qi = 0; qi < 3; ++qi)
#pragma unroll
            for (int j = 0; j < 4; ++j) {
                if (BFX) {
                    asm volatile("" :: "v"(xv[qi][j]));
                } else {
                    asm volatile("" :: "v"(xf[qi][j][0]));
                    asm volatile("" :: "v"(xf[qi][j][1]));
                }
            }

        // ---- Stage 1: barrier-free per-wave loop over own 4 queries ----
        float4v frag[4][4];
#pragma unroll
        for (int qi = 0; qi < 4; ++qi)
#pragma unroll
            for (int v = 0; v < 4; ++v) frag[qi][v] = (float4v){0.f, 0.f, 0.f, 0.f};

#pragma unroll
        for (int qi = 0; qi < 4; ++qi) {
#pragma unroll
            for (int j = 0; j < 4; ++j) {
                short8 pv;
                if (BFX) {
                    pv = xv[qi][j];
                } else {
                    const float4v a0 = xf[qi][j][0], a1 = xf[qi][j][1];
                    pv[0] = (short)f2bf(a0[0]); pv[1] = (short)f2bf(a0[1]);
                    pv[2] = (short)f2bf(a0[2]); pv[3] = (short)f2bf(a0[3]);
                    pv[4] = (short)f2bf(a1[0]); pv[5] = (short)f2bf(a1[1]);
                    pv[6] = (short)f2bf(a1[2]); pv[7] = (short)f2bf(a1[3]);
                }
                *(short8*)&xn_own[Eb + j * 64] = pv;
            }
            __builtin_amdgcn_sched_barrier(0);   // pin stores before asm reads

            short4v a0, a1, b0[4], b1[4];
            asm volatile("ds_read_b64_tr_b16 %0, %1 offset:%c2"
                         : "=v"(a0) : "v"(wtb), "i"(qi * 1024) : "memory");
            asm volatile("ds_read_b64_tr_b16 %0, %1 offset:%c2"
                         : "=v"(a1) : "v"(wtb), "i"(qi * 1024 + 512) : "memory");
#pragma unroll
            for (int v = 0; v < 4; ++v) {
                asm volatile("ds_read_b64_tr_b16 %0, %1 offset:%c2"
                             : "=v"(b0[v]) : "v"(xnb), "i"(v * 1056) : "memory");
                asm volatile("ds_read_b64_tr_b16 %0, %1 offset:%c2"
                             : "=v"(b1[v]) : "v"(xnb), "i"(v * 1056 + 512) : "memory");
            }
            asm volatile("s_waitcnt lgkmcnt(0)");
            __builtin_amdgcn_sched_barrier(0);   // rule #18: no MFMA hoist past the wait

            short8 a;
#pragma unroll
            for (int e = 0; e < 4; ++e) { a[e] = a0[e]; a[e + 4] = a1[e]; }
#pragma unroll
            for (int v = 0; v < 4; ++v) {
                short8 bb;
#pragma unroll
                for (int e = 0; e < 4; ++e) { bb[e] = b0[v][e]; bb[e + 4] = b1[v][e]; }
                frag[qi][v] = __builtin_amdgcn_mfma_f32_16x16x32_bf16(a, bb, frag[qi][v], 0, 0, 0);
            }
        }

        __syncthreads();   // all waves done with xn/wT2 before Awt overwrites

        // ---- Round trip: C-frags -> Awt (k' = f*16 + kq, b64 writes) ----
        char* AwtB = (char*)lds;
#pragma unroll
        for (int qi = 0; qi < 4; ++qi) {
            const int qg = wv * 4 + qi;
            char* qb = AwtB + qg * 2048;
            const int xr = ((qg & 7) << 4) ^ (((qg >> 3) & 1) << 3) ^ ((ml >> 2) << 3);
#pragma unroll
            for (int v = 0; v < 4; ++v) {
                short4v w;
#pragma unroll
                for (int r = 0; r < 4; ++r) w[r] = (short)f2bf(frag[qi][v][r]);
                const int Bw = (v * 16 + ml) * 32 + quad * 8;
                *(short4v*)(qb + (Bw ^ xr)) = w;
            }
        }
        __syncthreads();

        // ---- Stage 2: out[q][o] = sum_{k'} Awt[q][k'] * W'[k'][o] ----
        float4v acc0 = (float4v){0.f, 0.f, 0.f, 0.f};
        float4v acc1 = (float4v){0.f, 0.f, 0.f, 0.f};
        const short* bptr = Bfrag + (wv * 32) * 512 + lane * 8;
        const char*  arow = AwtB + ml * 2048;
        const int    xr2  = ((ml & 7) << 4) ^ (((ml >> 3) & 1) << 3);
#pragma unroll 2
        for (int t = 0; t < 32; t += 2) {
            {
                const int Br = t * 64 + quad * 16;
                const int ad = Br ^ xr2 ^ (((t >> 1) & 3) << 3);
                const short4v alo = *(const short4v*)(arow + ad);
                const short4v ahi = *(const short4v*)(arow + (ad ^ 8));
                short8 a;
#pragma unroll
                for (int e = 0; e < 4; ++e) { a[e] = alo[e]; a[e + 4] = ahi[e]; }
                const short8 bb = *(const short8*)(bptr + t * 512);
                acc0 = __builtin_amdgcn_mfma_f32_16x16x32_bf16(a, bb, acc0, 0, 0, 0);
            }
            {
                const int t1 = t + 1;
                const int Br = t1 * 64 + quad * 16;
                const int ad = Br ^ xr2 ^ (((t1 >> 1) & 3) << 3);
                const short4v alo = *(const short4v*)(arow + ad);
                const short4v ahi = *(const short4v*)(arow + (ad ^ 8));
                short8 a;
#pragma unroll
                for (int e = 0; e < 4; ++e) { a[e] = alo[e]; a[e + 4] = ahi[e]; }
                const short8 bb = *(const short8*)(bptr + t1 * 512);
                acc1 = __builtin_amdgcn_mfma_f32_16x16x32_bf16(a, bb, acc1, 0, 0, 0);
            }
        }
        const float4v acc = acc0 + acc1;

        // ---- Epilogue: raw out write + per-channel partial accumulation ----
#pragma unroll
        for (int r = 0; r < 4; ++r) {
            const float v = acc[r];
            out[(q0 + quad * 4 + r) * OUTC + wv * 16 + ml] = v;
            s_tot  += v;
            s2_tot += v * v;
        }
        __syncthreads();   // protect LDS (Awt) from next tile's xn/wT2 writes
    }

    // one shfl-reduction + one atomicAdd per channel per block
    s_tot  += __shfl_xor(s_tot, 16, 64);  s_tot  += __shfl_xor(s_tot, 32, 64);
    s2_tot += __shfl_xor(s2_tot, 16, 64); s2_tot += __shfl_xor(s2_tot, 32, 64);
    if (quad == 0) {
        const int c = wv * 16 + ml;
        atomicAdd(&gsum[c], s_tot);
        atomicAdd(&gsum[64 + c], s2_tot);
    }
    __threadfence();
    cg::this_grid().sync();

    // ---------------- Phase 2: BN + LeakyReLU in place ----------------
    float* scf = (float*)lds;        // reuse LDS (phase-1 data dead)
    float* shf = scf + 64;
    if (tid < 64) {
        const float S = gsum[tid], Q = gsum[64 + tid];
        const float mean = S * (1.0f / (float)NQ);
        const float var  = Q * (1.0f / (float)NQ) - mean * mean;
        const float scale = gamma[tid] / sqrtf(var + 1e-5f);
        scf[tid] = scale;
        shf[tid] = beta[tid] - mean * scale;
    }
    __syncthreads();
    for (unsigned e = blockIdx.x * 256u + tid; e < 1048576u; e += (unsigned)G * 256u) {
        float4 v = ((const float4*)out)[e];
        const int cgi = (e & 15) * 4;
        float4 r;
        r.x = v.x * scf[cgi + 0] + shf[cgi + 0];
        r.y = v.y * scf[cgi + 1] + shf[cgi + 1];
        r.z = v.z * scf[cgi + 2] + shf[cgi + 2];
        r.w = v.w * scf[cgi + 3] + shf[cgi + 3];
        r.x = r.x >= 0.0f ? r.x : 0.1f * r.x;
        r.y = r.y >= 0.0f ? r.y : 0.1f * r.y;
        r.z = r.z >= 0.0f ? r.z : 0.1f * r.z;
        r.w = r.w >= 0.0f ? r.w : 0.1f * r.w;
        ((float4*)out)[e] = r;
    }
}

// ===========================================================================
// Legacy 4-kernel path (R5, verified) -- used only if cooperative launch fails
// ===========================================================================
__global__ __launch_bounds__(256) void prep_all(
    const float* __restrict__ W, const float* __restrict__ x,
    short* __restrict__ Bfrag, unsigned short* __restrict__ xbf, int do_x)
{
    const int b = blockIdx.x;
    if (b < 4096) {
        if (do_x) {
            const int t = b * 256 + threadIdx.x;
            const float4 v = ((const float4*)x)[t];
            uint2 p; p.x = pk2(v.x, v.y); p.y = pk2(v.z, v.w);
            ((uint2*)xbf)[t] = p;
        }
    } else {
        const int t2  = (b - 4096) * 256 + threadIdx.x;
        const int j   = t2 & 7;
        const int ln  = (t2 >> 3) & 63;
        const int tt  = (t2 >> 9) & 31;
        const int wvq = t2 >> 14;
        const int kp2 = tt * 32 + (ln >> 4) * 8 + j;
        const int kq  = kp2 & 15;
        const int ii  = kp2 >> 4;
        const int oo  = wvq * 16 + (ln & 15);
        const float val = (kq < K) ? W[(kq * 64 + ii) * 64 + oo] : 0.0f;
        Bfrag[t2] = (short)f2bf(val);
    }
}

template<bool BFX>
__global__ __launch_bounds__(256, 5) void kpconv_mfma(
    const float* __restrict__ x, const unsigned short* __restrict__ xbf,
    const float* __restrict__ qp, const float* __restrict__ sp,
    const int* __restrict__ inds, const float* __restrict__ kp,
    const short* __restrict__ Bfrag, float* __restrict__ out_raw,
    float* __restrict__ psum)
{
    __shared__ __align__(16) short lds[16384];
    short* xn  = lds;
    short* wT2 = lds + 8448;

    const int tid  = threadIdx.x;
    const int lane = tid & 63;
    const int wv   = tid >> 6;
    const int quad = lane >> 4;
    const int ml   = lane & 15;
    const int q8   = lane >> 3;
    const int m8   = lane & 7;
    const int q0   = blockIdx.x * QB;

    short* xn_own = xn + wv * 2112;

    short8  xv[4][4];
    float4v xf[4][4][2];
#pragma unroll
    for (int qi = 0; qi < 4; ++qi) {
        const int ibase = (q0 + wv * 4 + qi) * H;
#pragma unroll
        for (int j = 0; j < 4; ++j) {
            const int id = inds[ibase + j * 8 + q8];
            if (BFX) {
                xv[qi][j] = *(const short8*)((const short*)xbf + id * IN + m8 * 8);
            } else {
                xf[qi][j][0] = *(const float4v*)(x + id * IN + m8 * 8);
                xf[qi][j][1] = *(const float4v*)(x + id * IN + m8 * 8 + 4);
            }
        }
    }

#pragma unroll
    for (int rep = 0; rep < 2; ++rep) {
        const int p  = lane + rep * 64;
        const int qi = p >> 5, h = p & 31;
        const int qg = wv * 4 + qi;
        const int n  = q0 + qg;
        const int id = inds[n * H + h];
        const float dx = sp[id * 3 + 0] - qp[n * 3 + 0];
        const float dy = sp[id * 3 + 1] - qp[n * 3 + 1];
        const float dz = sp[id * 3 + 2] - qp[n * 3 + 2];
        short8 w0, w1;
#pragma unroll
        for (int k = 0; k < K; ++k) {
            const float ex = dx - kp[k * 3 + 0];
            const float ey = dy - kp[k * 3 + 1];
            const float ez = dz - kp[k * 3 + 2];
            const float sq = ex * ex + ey * ey + ez * ez;
            float wval = 1.0f - __builtin_amdgcn_sqrtf(sq) * INV_EXT;
            wval = wval > 0.0f ? wval : 0.0f;
            if (k < 8) w0[k]     = (short)f2bf(wval);
            else       w1[k - 8] = (short)f2bf(wval);
        }
        w1[7] = 0;
        short* dst = wT2 + qg * 512 + ((h >> 2) & 1) * 256 + (h >> 3) * 64 + (h & 3) * 16;
        *(short8*)dst       = w0;
        *(short8*)(dst + 8) = w1;
    }

#pragma unroll
    for (int qi = 0; qi < 3; ++qi)
#pragma unroll
        for (int j = 0; j < 4; ++j) {
            if (BFX) {
                asm volatile("" :: "v"(xv[qi][j]));
            } else {
                asm volatile("" :: "v"(xf[qi][j][0]));
                asm volatile("" :: "v"(xf[qi][j][1]));
            }
        }

    const unsigned ldsb = (unsigned)(size_t)(&lds[0]);
    const unsigned xnb  = ldsb + (unsigned)(wv * 4224 + lane * 8);
    const unsigned wtb  = ldsb + 16896u + (unsigned)(wv * 4096 + lane * 8);

    float4v frag[4][4];
#pragma unroll
    for (int qi = 0; qi < 4; ++qi)
#pragma unroll
        for (int v = 0; v < 4; ++v) frag[qi][v] = (float4v){0.f, 0.f, 0.f, 0.f};

    const int Eb = (m8 >> 1) * 528 + ((q8 >> 2) & 1) * 256 + (q8 & 3) * 16 + (m8 & 1) * 8;

#pragma unroll
    for (int qi = 0; qi < 4; ++qi) {
#pragma unroll
        for (int j = 0; j < 4; ++j) {
            short8 pv;
            if (BFX) {
                pv = xv[qi][j];
            } else {
                const float4v a0 = xf[qi][j][0], a1 = xf[qi][j][1];
                pv[0] = (short)f2bf(a0[0]); pv[1] = (short)f2bf(a0[1]);
                pv[2] = (short)f2bf(a0[2]); pv[3] = (short)f2bf(a0[3]);
                pv[4] = (short)f2bf(a1[0]); pv[5] = (short)f2bf(a1[1]);
                pv[6] = (short)f2bf(a1[2]); pv[7] = (short)f2bf(a1[3]);
            }
            *(short8*)&xn_own[Eb + j * 64] = pv;
        }
        __builtin_amdgcn_sched_barrier(0);

        short4v a0, a1, b0[4], b1[4];
        asm volatile("ds_read_b64_tr_b16 %0, %1 offset:%c2"
                     : "=v"(a0) : "v"(wtb), "i"(qi * 1024) : "memory");
        asm volatile("ds_read_b64_tr_b16 %0, %1 offset:%c2"
                     : "=v"(a1) : "v"(wtb), "i"(qi * 1024 + 512) : "memory");
#pragma unroll
        for (int v = 0; v < 4; ++v) {
            asm volatile("ds_read_b64_tr_b16 %0, %1 offset:%c2"
                         : "=v"(b0[v]) : "v"(xnb), "i"(v * 1056) : "memory");
            asm volatile("ds_read_b64_tr_b16 %0, %1 offset:%c2"
                         : "=v"(b1[v]) : "v"(xnb), "i"(v * 1056 + 512) : "memory");
        }
        asm volatile("s_waitcnt lgkmcnt(0)");
        __builtin_amdgcn_sched_barrier(0);

        short8 a;
#pragma unroll
        for (int e = 0; e < 4; ++e) { a[e] = a0[e]; a[e + 4] = a1[e]; }
#pragma unroll
        for (int v = 0; v < 4; ++v) {
            short8 bb;
#pragma unroll
            for (int e = 0; e < 4; ++e) { bb[e] = b0[v][e]; bb[e + 4] = b1[v][e]; }
            frag[qi][v] = __builtin_amdgcn_mfma_f32_16x16x32_bf16(a, bb, frag[qi][v], 0, 0, 0);
        }
    }

    __syncthreads();

    char* AwtB = (char*)lds;
#pragma unroll
    for (int qi = 0; qi < 4; ++qi) {
        const int qg = wv * 4 + qi;
        char* qb = AwtB + qg * 2048;
        const int xr = ((qg & 7) << 4) ^ (((qg >> 3) & 1) << 3) ^ ((ml >> 2) << 3);
#pragma unroll
        for (int v = 0; v < 4; ++v) {
            short4v w;
#pragma unroll
            for (int r = 0; r < 4; ++r) w[r] = (short)f2bf(frag[qi][v][r]);
            const int Bw = (v * 16 + ml) * 32 + quad * 8;
            *(short4v*)(qb + (Bw ^ xr)) = w;
        }
    }
    __syncthreads();

    float4v acc0 = (float4v){0.f, 0.f, 0.f, 0.f};
    float4v acc1 = (float4v){0.f, 0.f, 0.f, 0.f};
    const short* bptr = Bfrag + (wv * 32) * 512 + lane * 8;
    const char*  arow = AwtB + ml * 2048;
    const int    xr2  = ((ml & 7) << 4) ^ (((ml >> 3) & 1) << 3);
#pragma unroll 2
    for (int t = 0; t < 32; t += 2) {
        {
            const int Br = t * 64 + quad * 16;
            const int ad = Br ^ xr2 ^ (((t >> 1) & 3) << 3);
            const short4v alo = *(const short4v*)(arow + ad);
            const short4v ahi = *(const short4v*)(arow + (ad ^ 8));
            short8 a;
#pragma unroll
            for (int e = 0; e < 4; ++e) { a[e] = alo[e]; a[e + 4] = ahi[e]; }
            const short8 bb = *(const short8*)(bptr + t * 512);
            acc0 = __builtin_amdgcn_mfma_f32_16x16x32_bf16(a, bb, acc0, 0, 0, 0);
        }
        {
            const int t1 = t + 1;
            const int Br = t1 * 64 + quad * 16;
            const int ad = Br ^ xr2 ^ (((t1 >> 1) & 3) << 3);
            const short4v alo = *(const short4v*)(arow + ad);
            const short4v ahi = *(const short4v*)(arow + (ad ^ 8));
            short8 a;
#pragma unroll
            for (int e = 0; e < 4; ++e) { a[e] = alo[e]; a[e + 4] = ahi[e]; }
            const short8 bb = *(const short8*)(bptr + t1 * 512);
            acc1 = __builtin_amdgcn_mfma_f32_16x16x32_bf16(a, bb, acc1, 0, 0, 0);
        }
    }
    const float4v acc = acc0 + acc1;

    float s = 0.f, s2 = 0.f;
#pragma unroll
    for (int r = 0; r < 4; ++r) {
        const float v = acc[r];
        out_raw[(q0 + quad * 4 + r) * OUTC + wv * 16 + ml] = v;
        s += v; s2 += v * v;
    }
    s  += __shfl_xor(s, 16, 64);  s  += __shfl_xor(s, 32, 64);
    s2 += __shfl_xor(s2, 16, 64); s2 += __shfl_xor(s2, 32, 64);
    if (quad == 0) {
        const int c = wv * 16 + ml;
        psum[c * 4096 + blockIdx.x]          = s;
        psum[262144 + c * 4096 + blockIdx.x] = s2;
    }
}

__global__ __launch_bounds__(256) void bn_stats(
    const float* __restrict__ psum, const float* __restrict__ gamma,
    const float* __restrict__ beta, float* __restrict__ sc_sh)
{
    const int c = blockIdx.x;
    const int t = threadIdx.x;
    float s = 0.f, q = 0.f;
#pragma unroll
    for (int i = 0; i < 16; ++i) {
        s += psum[c * 4096 + t + i * 256];
        q += psum[262144 + c * 4096 + t + i * 256];
    }
    __shared__ float rs[4], rq[4];
#pragma unroll
    for (int off = 32; off; off >>= 1) {
        s += __shfl_down(s, off, 64);
        q += __shfl_down(q, off, 64);
    }
    if ((t & 63) == 0) { rs[t >> 6] = s; rq[t >> 6] = q; }
    __syncthreads();
    if (t == 0) {
        s = rs[0] + rs[1] + rs[2] + rs[3];
        q = rq[0] + rq[1] + rq[2] + rq[3];
        const float mean = s * (1.0f / (float)NQ);
        const float var  = q * (1.0f / (float)NQ) - mean * mean;
        const float scale = gamma[c] / sqrtf(var + 1e-5f);
        sc_sh[c]      = scale;
        sc_sh[64 + c] = beta[c] - mean * scale;
    }
}

__global__ __launch_bounds__(256) void bn_apply(
    float* __restrict__ out, const float* __restrict__ sc_sh)
{
    __shared__ float sc[64];
    __shared__ float sh[64];
    if (threadIdx.x < 64) {
        sc[threadIdx.x] = sc_sh[threadIdx.x];
        sh[threadIdx.x] = sc_sh[64 + threadIdx.x];
    }
    __syncthreads();
    const int idx = blockIdx.x * 256 + threadIdx.x;
#pragma unroll
    for (int it = 0; it < 4; ++it) {
        const int e = idx + it * 262144;
        float4 v = ((const float4*)out)[e];
        const int cg = (e & 15) * 4;
        float4 r;
        r.x = v.x * sc[cg + 0] + sh[cg + 0];
        r.y = v.y * sc[cg + 1] + sh[cg + 1];
        r.z = v.z * sc[cg + 2] + sh[cg + 2];
        r.w = v.w * sc[cg + 3] + sh[cg + 3];
        r.x = r.x >= 0.0f ? r.x : 0.1f * r.x;
        r.y = r.y >= 0.0f ? r.y : 0.1f * r.y;
        r.z = r.z >= 0.0f ? r.z : 0.1f * r.z;
        r.w = r.w >= 0.0f ? r.w : 0.1f * r.w;
        ((float4*)out)[e] = r;
    }
}

// ---------------------------------------------------------------------------
extern "C" void kernel_launch(void* const* d_in, const int* in_sizes, int n_in,
                              void* d_out, int out_size, void* d_ws, size_t ws_size,
                              hipStream_t stream)
{
    (void)in_sizes; (void)n_in; (void)out_size;
    const float* x     = (const float*)d_in[0];
    const float* qp    = (const float*)d_in[1];
    const float* sp    = (const float*)d_in[2];
    const int*   inds  = (const int*)d_in[3];
    const float* kp    = (const float*)d_in[4];
    const float* W     = (const float*)d_in[5];
    const float* gamma = (const float*)d_in[6];
    const float* beta  = (const float*)d_in[7];
    float* out = (float*)d_out;

    short*          Bfrag = (short*)d_ws;
    float*          psum  = (float*)((char*)d_ws + OFF_PSUM);
    float*          gsum  = (float*)((char*)d_ws + OFF_SCSH);
    unsigned short* xbf   = (unsigned short*)((char*)d_ws + OFF_XBF);

    const int use_bf = (ws_size >= NEED_BF16) ? 1 : 0;

    // --- cooperative fused path ---
    int nb = 0;
    hipError_t qerr;
    if (use_bf)
        qerr = hipOccupancyMaxActiveBlocksPerMultiprocessor(&nb, kpconv_fused<true>, 256, 0);
    else
        qerr = hipOccupancyMaxActiveBlocksPerMultiprocessor(&nb, kpconv_fused<false>, 256, 0);
    if (qerr != hipSuccess || nb < 1) nb = 1;
    int grid = nb * 256;
    if (grid > NTILE) grid = NTILE;
    if (grid < 256) grid = 256;

    void* args[12];
    args[0]  = (void*)&x;     args[1]  = (void*)&xbf;
    args[2]  = (void*)&qp;    args[3]  = (void*)&sp;
    args[4]  = (void*)&inds;  args[5]  = (void*)&kp;
    args[6]  = (void*)&Bfrag; args[7]  = (void*)&W;
    args[8]  = (void*)&gamma; args[9]  = (void*)&beta;
    args[10] = (void*)&out;   args[11] = (void*)&gsum;

    hipError_t lerr;
    if (use_bf)
        lerr = hipLaunchCooperativeKernel(kpconv_fused<true>,  dim3(grid), dim3(256), args, 0, stream);
    else
        lerr = hipLaunchCooperativeKernel(kpconv_fused<false>, dim3(grid), dim3(256), args, 0, stream);

    if (lerr != hipSuccess) {
        // --- legacy 4-kernel fallback (R5 path, verified) ---
        (void)hipGetLastError();
        prep_all<<<4352, 256, 0, stream>>>(W, x, Bfrag, xbf, use_bf);
        if (use_bf)
            kpconv_mfma<true><<<NQ / QB, 256, 0, stream>>>(x, xbf, qp, sp, inds, kp, Bfrag, out, psum);
        else
            kpconv_mfma<false><<<NQ / QB, 256, 0, stream>>>(x, xbf, qp, sp, inds, kp, Bfrag, out, psum);
        bn_stats<<<64, 256, 0, stream>>>(psum, gamma, beta, gsum);
        bn_apply<<<1024, 256, 0, stream>>>(out, gsum);
    }
}

// Round 7
// 203.170 us; speedup vs baseline: 1.8026x; 1.8026x over previous
//
#include <hip/hip_runtime.h>
#include <math.h>

// Problem constants
#define NQ   65536
#define H    32
#define IN   64
#define OUTC 64
#define K    15
#define QB   16          // queries per block
#define INV_EXT (1.0f / 0.048f)

// d_ws layout (bytes)
#define OFF_PSUM  131072                       // Bfrag region: 65536 shorts = 128 KB exact
#define OFF_SCSH  (OFF_PSUM + 2097152)         // 128 floats (gsum: s[64], s2[64])
#define OFF_XBF   (OFF_SCSH + 1024)            // x in bf16: 8 MB
#define NEED_BF16 (OFF_XBF + (size_t)NQ * IN * 2)

typedef __attribute__((ext_vector_type(8))) short short8;
typedef __attribute__((ext_vector_type(4))) short short4v;
typedef __attribute__((ext_vector_type(4))) float float4v;

static __device__ __forceinline__ unsigned short f2bf(float f) {
    return (unsigned short)((__float_as_uint(f) + 0x8000u) >> 16);
}
static __device__ __forceinline__ unsigned pk2(float a, float b) {
    return (__float_as_uint(a) + 0x8000u) >> 16 |
           ((__float_as_uint(b) + 0x8000u) & 0xFFFF0000u);
}

// ---------------------------------------------------------------------------
// Prep: blocks [0,4096): x fp32 -> bf16 (coalesced).
//       blocks [4096,4352): W repack; block 4096 also zeroes gsum[128].
// R19: gsum zeroing added (BN partials now atomically accumulated by main).
// ---------------------------------------------------------------------------
__global__ __launch_bounds__(256) void prep_all(
    const float* __restrict__ W, const float* __restrict__ x,
    short* __restrict__ Bfrag, unsigned short* __restrict__ xbf,
    float* __restrict__ gsum, int do_x)
{
    const int b = blockIdx.x;
    if (b < 4096) {
        if (do_x) {
            const int t = b * 256 + threadIdx.x;      // float4 index
            const float4 v = ((const float4*)x)[t];
            uint2 p; p.x = pk2(v.x, v.y); p.y = pk2(v.z, v.w);
            ((uint2*)xbf)[t] = p;
        }
    } else {
        if (b == 4096 && threadIdx.x < 128) gsum[threadIdx.x] = 0.0f;
        const int t2  = (b - 4096) * 256 + threadIdx.x;   // 0..65535
        const int j   = t2 & 7;
        const int ln  = (t2 >> 3) & 63;
        const int tt  = (t2 >> 9) & 31;
        const int wvq = t2 >> 14;
        const int kp2 = tt * 32 + (ln >> 4) * 8 + j;      // k' = i*16 + kq
        const int kq  = kp2 & 15;
        const int ii  = kp2 >> 4;
        const int oo  = wvq * 16 + (ln & 15);
        const float val = (kq < K) ? W[(kq * 64 + ii) * 64 + oo] : 0.0f;
        Bfrag[t2] = (short)f2bf(val);
    }
}

// ---------------------------------------------------------------------------
// Main kernel. R19 = R5 body (verified, 60 us) with ONE change: BN partials
// go straight to gsum via atomicAdd (1 add per channel per block; 4096
// adds/address over ~60 us = one per ~35 cyc -- negligible contention).
// Eliminates the bn_stats kernel + the 2 MB psum round trip.
// R6's cooperative fusion is REVERTED: grid-strided tile loop collapsed
// memory-level parallelism 6x (423 us, hbm 391 GB/s) -- fresh-block dispatch
// is what keeps the gather pipeline full.
// ---------------------------------------------------------------------------
template<bool BFX>
__global__ __launch_bounds__(256, 5) void kpconv_mfma(
    const float* __restrict__ x, const unsigned short* __restrict__ xbf,
    const float* __restrict__ qp, const float* __restrict__ sp,
    const int* __restrict__ inds, const float* __restrict__ kp,
    const short* __restrict__ Bfrag, float* __restrict__ out_raw,
    float* __restrict__ gsum)
{
    __shared__ __align__(16) short lds[16384];            // 32768 B exact
    short* xn  = lds;                                     // 4 waves x 2112 shorts, staggered
    short* wT2 = lds + 8448;                              // [16 qg][512] tr-layout

    const int tid  = threadIdx.x;
    const int lane = tid & 63;
    const int wv   = tid >> 6;
    const int quad = lane >> 4;
    const int ml   = lane & 15;
    const int q8   = lane >> 3;                           // neighbor slot 0..7 (contiguous lanes)
    const int m8   = lane & 7;                            // feat octet 0..7
    const int q0   = blockIdx.x * QB;

    short* xn_own = xn + wv * 2112;                       // wave-private tr buffer (4224 B)

    // ---- Prefetch ALL 4 queries' gathers: 16B/lane, coalesced (8 lanes/row)
    short8  xv[4][4];
    float4v xf[4][4][2];
#pragma unroll
    for (int qi = 0; qi < 4; ++qi) {
        const int ibase = (q0 + wv * 4 + qi) * H;
#pragma unroll
        for (int j = 0; j < 4; ++j) {
            const int id = inds[ibase + j * 8 + q8];
            if (BFX) {
                xv[qi][j] = *(const short8*)((const short*)xbf + id * IN + m8 * 8);
            } else {
                xf[qi][j][0] = *(const float4v*)(x + id * IN + m8 * 8);
                xf[qi][j][1] = *(const float4v*)(x + id * IN + m8 * 8 + 4);
            }
        }
    }

    // ---- Stage A: influence weights -> wT2 tr-layout (2 x b128 per lane/rep)
    // wT2 elem(qg,h,kq) = qg*512 + ((h>>2)&1)*256 + (h>>3)*64 + (h&3)*16 + kq
#pragma unroll
    for (int rep = 0; rep < 2; ++rep) {
        const int p  = lane + rep * 64;      // 0..127
        const int qi = p >> 5, h = p & 31;
        const int qg = wv * 4 + qi;
        const int n  = q0 + qg;
        const int id = inds[n * H + h];
        const float dx = sp[id * 3 + 0] - qp[n * 3 + 0];
        const float dy = sp[id * 3 + 1] - qp[n * 3 + 1];
        const float dz = sp[id * 3 + 2] - qp[n * 3 + 2];
        short8 w0, w1;
#pragma unroll
        for (int k = 0; k < K; ++k) {
            const float ex = dx - kp[k * 3 + 0];
            const float ey = dy - kp[k * 3 + 1];
            const float ez = dz - kp[k * 3 + 2];
            const float sq = ex * ex + ey * ey + ez * ez;
            float wval = 1.0f - __builtin_amdgcn_sqrtf(sq) * INV_EXT;
            wval = wval > 0.0f ? wval : 0.0f;
            if (k < 8) w0[k]     = (short)f2bf(wval);
            else       w1[k - 8] = (short)f2bf(wval);
        }
        w1[7] = 0;                           // kq = 15 zero column
        short* dst = wT2 + qg * 512 + ((h >> 2) & 1) * 256 + (h >> 3) * 64 + (h & 3) * 16;
        *(short8*)dst       = w0;
        *(short8*)(dst + 8) = w1;
    }
    // no barrier: wT2 rows qg in [4wv,4wv+4) are read only by this wave

    // Pin 12/16 prefetched values live HERE (input-only asm uses on
    // ext-vector values: they must exist by this point -> loads can't sink).
#pragma unroll
    for (int qi = 0; qi < 3; ++qi)
#pragma unroll
        for (int j = 0; j < 4; ++j) {
            if (BFX) {
                asm volatile("" :: "v"(xv[qi][j]));
            } else {
                asm volatile("" :: "v"(xf[qi][j][0]));
                asm volatile("" :: "v"(xf[qi][j][1]));
            }
        }

    // tr-read per-lane base addresses (addr = base + lane*8; 128B/16-lane group)
    const unsigned ldsb = (unsigned)(size_t)(&lds[0]);
    const unsigned xnb  = ldsb + (unsigned)(wv * 4224 + lane * 8);
    const unsigned wtb  = ldsb + 16896u + (unsigned)(wv * 4096 + lane * 8);

    // ---- Stage 1: barrier-free per-wave loop over own 4 queries ----
    float4v frag[4][4];
#pragma unroll
    for (int qi = 0; qi < 4; ++qi)
#pragma unroll
        for (int v = 0; v < 4; ++v) frag[qi][v] = (float4v){0.f, 0.f, 0.f, 0.f};

    // xn write base (shorts): v-stride 528 (=1056B) -> write phase covers all
    // 32 banks: slots {0,16,1056,1072,2112,2128,3168,3184}B.
    const int Eb = (m8 >> 1) * 528 + ((q8 >> 2) & 1) * 256 + (q8 & 3) * 16 + (m8 & 1) * 8;

#pragma unroll
    for (int qi = 0; qi < 4; ++qi) {
        // write prefetched rows into tr layout
#pragma unroll
        for (int j = 0; j < 4; ++j) {
            short8 pv;
            if (BFX) {
                pv = xv[qi][j];
            } else {
                const float4v a0 = xf[qi][j][0], a1 = xf[qi][j][1];
                pv[0] = (short)f2bf(a0[0]); pv[1] = (short)f2bf(a0[1]);
                pv[2] = (short)f2bf(a0[2]); pv[3] = (short)f2bf(a0[3]);
                pv[4] = (short)f2bf(a1[0]); pv[5] = (short)f2bf(a1[1]);
                pv[6] = (short)f2bf(a1[2]); pv[7] = (short)f2bf(a1[3]);
            }
            *(short8*)&xn_own[Eb + j * 64] = pv;
        }
        __builtin_amdgcn_sched_barrier(0);   // pin stores before asm reads

        short4v a0, a1, b0[4], b1[4];
        asm volatile("ds_read_b64_tr_b16 %0, %1 offset:%c2"
                     : "=v"(a0) : "v"(wtb), "i"(qi * 1024) : "memory");
        asm volatile("ds_read_b64_tr_b16 %0, %1 offset:%c2"
                     : "=v"(a1) : "v"(wtb), "i"(qi * 1024 + 512) : "memory");
#pragma unroll
        for (int v = 0; v < 4; ++v) {
            asm volatile("ds_read_b64_tr_b16 %0, %1 offset:%c2"
                         : "=v"(b0[v]) : "v"(xnb), "i"(v * 1056) : "memory");
            asm volatile("ds_read_b64_tr_b16 %0, %1 offset:%c2"
                         : "=v"(b1[v]) : "v"(xnb), "i"(v * 1056 + 512) : "memory");
        }
        asm volatile("s_waitcnt lgkmcnt(0)");
        __builtin_amdgcn_sched_barrier(0);   // rule #18: no MFMA hoist past the wait

        short8 a;
#pragma unroll
        for (int e = 0; e < 4; ++e) { a[e] = a0[e]; a[e + 4] = a1[e]; }
#pragma unroll
        for (int v = 0; v < 4; ++v) {
            short8 bb;
#pragma unroll
            for (int e = 0; e < 4; ++e) { bb[e] = b0[v][e]; bb[e + 4] = b1[v][e]; }
            frag[qi][v] = __builtin_amdgcn_mfma_f32_16x16x32_bf16(a, bb, frag[qi][v], 0, 0, 0);
        }
    }

    __syncthreads();   // all waves done with xn/wT2 before Awt overwrites

    // ---- Round trip: C-frags -> Awt, k' = f*16 + kq (contiguous b64 writes)
    // swizzle: addr = B ^ ((q&7)<<4) ^ ((q>>3)<<3) ^ (((B>>7)&3)<<3)
    char* AwtB = (char*)lds;
#pragma unroll
    for (int qi = 0; qi < 4; ++qi) {
        const int qg = wv * 4 + qi;
        char* qb = AwtB + qg * 2048;
        const int xr = ((qg & 7) << 4) ^ (((qg >> 3) & 1) << 3) ^ ((ml >> 2) << 3);
#pragma unroll
        for (int v = 0; v < 4; ++v) {
            short4v w;
#pragma unroll
            for (int r = 0; r < 4; ++r) w[r] = (short)f2bf(frag[qi][v][r]);
            const int Bw = (v * 16 + ml) * 32 + quad * 8;
            *(short4v*)(qb + (Bw ^ xr)) = w;
        }
    }
    __syncthreads();

    // ---- Stage 2: out[q][o] = sum_{k'} Awt[q][k'] * W'[k'][o], K'=1024 ----
    // Even/odd accumulators: halve the serial MFMA dependency chain.
    float4v acc0 = (float4v){0.f, 0.f, 0.f, 0.f};
    float4v acc1 = (float4v){0.f, 0.f, 0.f, 0.f};
    const short* bptr = Bfrag + (wv * 32) * 512 + lane * 8;
    const char*  arow = AwtB + ml * 2048;
    const int    xr2  = ((ml & 7) << 4) ^ (((ml >> 3) & 1) << 3);
#pragma unroll 2
    for (int t = 0; t < 32; t += 2) {
        {
            const int Br = t * 64 + quad * 16;
            const int ad = Br ^ xr2 ^ (((t >> 1) & 3) << 3);
            const short4v alo = *(const short4v*)(arow + ad);
            const short4v ahi = *(const short4v*)(arow + (ad ^ 8));
            short8 a;
#pragma unroll
            for (int e = 0; e < 4; ++e) { a[e] = alo[e]; a[e + 4] = ahi[e]; }
            const short8 bb = *(const short8*)(bptr + t * 512);
            acc0 = __builtin_amdgcn_mfma_f32_16x16x32_bf16(a, bb, acc0, 0, 0, 0);
        }
        {
            const int t1 = t + 1;
            const int Br = t1 * 64 + quad * 16;
            const int ad = Br ^ xr2 ^ (((t1 >> 1) & 3) << 3);
            const short4v alo = *(const short4v*)(arow + ad);
            const short4v ahi = *(const short4v*)(arow + (ad ^ 8));
            short8 a;
#pragma unroll
            for (int e = 0; e < 4; ++e) { a[e] = alo[e]; a[e + 4] = ahi[e]; }
            const short8 bb = *(const short8*)(bptr + t1 * 512);
            acc1 = __builtin_amdgcn_mfma_f32_16x16x32_bf16(a, bb, acc1, 0, 0, 0);
        }
    }
    const float4v acc = acc0 + acc1;

    // ---- Epilogue: raw out write + atomic BN partials (R19) ----
    float s = 0.f, s2 = 0.f;
#pragma unroll
    for (int r = 0; r < 4; ++r) {
        const float v = acc[r];
        out_raw[(q0 + quad * 4 + r) * OUTC + wv * 16 + ml] = v;
        s += v; s2 += v * v;
    }
    s  += __shfl_xor(s, 16, 64);  s  += __shfl_xor(s, 32, 64);
    s2 += __shfl_xor(s2, 16, 64); s2 += __shfl_xor(s2, 32, 64);
    if (quad == 0) {
        const int c = wv * 16 + ml;
        atomicAdd(&gsum[c], s);
        atomicAdd(&gsum[64 + c], s2);
    }
}

// ---------------------------------------------------------------------------
// Apply BN + LeakyReLU(0.1) in place (float4). R19: computes scale/shift from
// the 128 atomic sums itself (bn_stats kernel eliminated).
// ---------------------------------------------------------------------------
__global__ __launch_bounds__(256) void bn_apply(
    float* __restrict__ out, const float* __restrict__ gsum,
    const float* __restrict__ gamma, const float* __restrict__ beta)
{
    __shared__ float sc[64];
    __shared__ float sh[64];
    if (threadIdx.x < 64) {
        const float S = gsum[threadIdx.x];
        const float Q = gsum[64 + threadIdx.x];
        const float mean = S * (1.0f / (float)NQ);
        const float var  = Q * (1.0f / (float)NQ) - mean * mean;
        const float scale = gamma[threadIdx.x] / sqrtf(var + 1e-5f);
        sc[threadIdx.x] = scale;
        sh[threadIdx.x] = beta[threadIdx.x] - mean * scale;
    }
    __syncthreads();
    const int idx = blockIdx.x * 256 + threadIdx.x;
#pragma unroll
    for (int it = 0; it < 4; ++it) {
        const int e = idx + it * 262144;
        float4 v = ((const float4*)out)[e];
        const int cg = (e & 15) * 4;
        float4 r;
        r.x = v.x * sc[cg + 0] + sh[cg + 0];
        r.y = v.y * sc[cg + 1] + sh[cg + 1];
        r.z = v.z * sc[cg + 2] + sh[cg + 2];
        r.w = v.w * sc[cg + 3] + sh[cg + 3];
        r.x = r.x >= 0.0f ? r.x : 0.1f * r.x;
        r.y = r.y >= 0.0f ? r.y : 0.1f * r.y;
        r.z = r.z >= 0.0f ? r.z : 0.1f * r.z;
        r.w = r.w >= 0.0f ? r.w : 0.1f * r.w;
        ((float4*)out)[e] = r;
    }
}

// ---------------------------------------------------------------------------
extern "C" void kernel_launch(void* const* d_in, const int* in_sizes, int n_in,
                              void* d_out, int out_size, void* d_ws, size_t ws_size,
                              hipStream_t stream)
{
    (void)in_sizes; (void)n_in; (void)out_size;
    const float* x     = (const float*)d_in[0];
    const float* qp    = (const float*)d_in[1];
    const float* sp    = (const float*)d_in[2];
    const int*   inds  = (const int*)d_in[3];
    const float* kp    = (const float*)d_in[4];
    const float* W     = (const float*)d_in[5];
    const float* gamma = (const float*)d_in[6];
    const float* beta  = (const float*)d_in[7];
    float* out = (float*)d_out;

    short*          Bfrag = (short*)d_ws;
    float*          gsum  = (float*)((char*)d_ws + OFF_SCSH);
    unsigned short* xbf   = (unsigned short*)((char*)d_ws + OFF_XBF);

    const int use_bf = (ws_size >= NEED_BF16) ? 1 : 0;

    prep_all<<<4352, 256, 0, stream>>>(W, x, Bfrag, xbf, gsum, use_bf);
    if (use_bf)
        kpconv_mfma<true><<<NQ / QB, 256, 0, stream>>>(x, xbf, qp, sp, inds, kp, Bfrag, out, gsum);
    else
        kpconv_mfma<false><<<NQ / QB, 256, 0, stream>>>(x, xbf, qp, sp, inds, kp, Bfrag, out, gsum);
    bn_apply<<<1024, 256, 0, stream>>>(out, gsum, gamma, beta);
}

// Round 9
// 146.675 us; speedup vs baseline: 2.4969x; 1.3852x over previous
//
#include <hip/hip_runtime.h>
#include <math.h>

// Problem constants
#define NQ   65536
#define H    32
#define IN   64
#define OUTC 64
#define K    15
#define QB   16          // queries per block
#define INV_EXT (1.0f / 0.048f)

// d_ws layout (bytes)
#define OFF_PSUM  131072                       // Bfrag region: 65536 shorts = 128 KB exact
#define OFF_SCSH  (OFF_PSUM + 2097152)         // 128 floats
#define OFF_XBF   (OFF_SCSH + 1024)            // x in bf16: 8 MB
#define NEED_BF16 (OFF_XBF + (size_t)NQ * IN * 2)

typedef __attribute__((ext_vector_type(8))) short short8;
typedef __attribute__((ext_vector_type(4))) short short4v;
typedef __attribute__((ext_vector_type(4))) float float4v;

static __device__ __forceinline__ unsigned short f2bf(float f) {
    return (unsigned short)((__float_as_uint(f) + 0x8000u) >> 16);
}
static __device__ __forceinline__ unsigned pk2(float a, float b) {
    return (__float_as_uint(a) + 0x8000u) >> 16 |
           ((__float_as_uint(b) + 0x8000u) & 0xFFFF0000u);
}

// ---------------------------------------------------------------------------
// Prep: blocks [0,4096): x fp32 -> bf16 (coalesced).
//       blocks [4096,4352): W repack -> stage-2 B-frag dump order with
//       k' = i*16 + kq (kq==15 is a zero row; K'=1024, 32 MFMA steps).
// ---------------------------------------------------------------------------
__global__ __launch_bounds__(256) void prep_all(
    const float* __restrict__ W, const float* __restrict__ x,
    short* __restrict__ Bfrag, unsigned short* __restrict__ xbf, int do_x)
{
    const int b = blockIdx.x;
    if (b < 4096) {
        if (do_x) {
            const int t = b * 256 + threadIdx.x;      // float4 index
            const float4 v = ((const float4*)x)[t];
            uint2 p; p.x = pk2(v.x, v.y); p.y = pk2(v.z, v.w);
            ((uint2*)xbf)[t] = p;
        }
    } else {
        const int t2  = (b - 4096) * 256 + threadIdx.x;   // 0..65535
        const int j   = t2 & 7;
        const int ln  = (t2 >> 3) & 63;
        const int tt  = (t2 >> 9) & 31;
        const int wvq = t2 >> 14;
        const int kp2 = tt * 32 + (ln >> 4) * 8 + j;      // k' = i*16 + kq
        const int kq  = kp2 & 15;
        const int ii  = kp2 >> 4;
        const int oo  = wvq * 16 + (ln & 15);
        const float val = (kq < K) ? W[(kq * 64 + ii) * 64 + oo] : 0.0f;
        Bfrag[t2] = (short)f2bf(val);
    }
}

// ---------------------------------------------------------------------------
// Main kernel. R22:
//  - R8's xn v-stride 928 REVERTED to 1056: a v-block's DATA is 1024B, so
//    stride 928 made adjacent v-blocks overlap by 96B -> corruption (the
//    absmax=3.37 failure). 1056 is the MINIMAL stride that is >=1024 and
//    == 32 (mod 128) for the conflict-free write phase.
//  - LDS declared honestly: 16640 shorts = 33280B (R5 used this layout but
//    declared 32768 -> 512B hidden OOB). 4 blocks/CU, launch_bounds(256,4).
//  - Stage-2 Awt on b128 KEPT, with corrected swizzle:
//      swz(B,q) = B ^ ((q&7)<<4) ^ (((B>>7)&3)<<4)   (both sides, involution)
//    bits >=4 only -> 16B granules contiguous; reads = 1 conflict-free b128
//    per MFMA (deletes the 8-elem a-repack); writes 2-way (free, m136).
//    Block-base consistency (B>>7 stable across the 8B/16B spans) verified.
// LDS phase1: xn 4x4224B=16896 + wT2 16384B = 33280B. Phase2: Awt 32768B.
// ---------------------------------------------------------------------------
template<bool BFX>
__global__ __launch_bounds__(256, 4) void kpconv_mfma(
    const float* __restrict__ x, const unsigned short* __restrict__ xbf,
    const float* __restrict__ qp, const float* __restrict__ sp,
    const int* __restrict__ inds, const float* __restrict__ kp,
    const short* __restrict__ Bfrag, float* __restrict__ out_raw,
    float* __restrict__ psum)
{
    __shared__ __align__(16) short lds[16640];            // 33280 B, all in bounds
    short* xn  = lds;                                     // 4 waves x 2112 shorts (1056B v-stride)
    short* wT2 = lds + 8448;                              // [16 qg][512] tr-layout

    const int tid  = threadIdx.x;
    const int lane = tid & 63;
    const int wv   = tid >> 6;
    const int quad = lane >> 4;
    const int ml   = lane & 15;
    const int q8   = lane >> 3;                           // neighbor slot 0..7 (contiguous lanes)
    const int m8   = lane & 7;                            // feat octet 0..7
    const int q0   = blockIdx.x * QB;

    short* xn_own = xn + wv * 2112;                       // wave-private tr buffer (4224 B)

    // ---- Prefetch ALL 4 queries' gathers: 16B/lane, coalesced (8 lanes/row)
    short8  xv[4][4];
    float4v xf[4][4][2];
#pragma unroll
    for (int qi = 0; qi < 4; ++qi) {
        const int ibase = (q0 + wv * 4 + qi) * H;
#pragma unroll
        for (int j = 0; j < 4; ++j) {
            const int id = inds[ibase + j * 8 + q8];
            if (BFX) {
                xv[qi][j] = *(const short8*)((const short*)xbf + id * IN + m8 * 8);
            } else {
                xf[qi][j][0] = *(const float4v*)(x + id * IN + m8 * 8);
                xf[qi][j][1] = *(const float4v*)(x + id * IN + m8 * 8 + 4);
            }
        }
    }

    // ---- Stage A: influence weights -> wT2 tr-layout (2 x b128 per lane/rep)
    // wT2 elem(qg,h,kq) = qg*512 + ((h>>2)&1)*256 + (h>>3)*64 + (h&3)*16 + kq
#pragma unroll
    for (int rep = 0; rep < 2; ++rep) {
        const int p  = lane + rep * 64;      // 0..127
        const int qi = p >> 5, h = p & 31;
        const int qg = wv * 4 + qi;
        const int n  = q0 + qg;
        const int id = inds[n * H + h];
        const float dx = sp[id * 3 + 0] - qp[n * 3 + 0];
        const float dy = sp[id * 3 + 1] - qp[n * 3 + 1];
        const float dz = sp[id * 3 + 2] - qp[n * 3 + 2];
        short8 w0, w1;
#pragma unroll
        for (int k = 0; k < K; ++k) {
            const float ex = dx - kp[k * 3 + 0];
            const float ey = dy - kp[k * 3 + 1];
            const float ez = dz - kp[k * 3 + 2];
            const float sq = ex * ex + ey * ey + ez * ez;
            float wval = 1.0f - __builtin_amdgcn_sqrtf(sq) * INV_EXT;
            wval = wval > 0.0f ? wval : 0.0f;
            if (k < 8) w0[k]     = (short)f2bf(wval);
            else       w1[k - 8] = (short)f2bf(wval);
        }
        w1[7] = 0;                           // kq = 15 zero column
        short* dst = wT2 + qg * 512 + ((h >> 2) & 1) * 256 + (h >> 3) * 64 + (h & 3) * 16;
        *(short8*)dst       = w0;
        *(short8*)(dst + 8) = w1;
    }
    // no barrier: wT2 rows qg in [4wv,4wv+4) are read only by this wave

    // Pin 12/16 prefetched values live HERE (input-only asm uses on
    // ext-vector values: they must exist by this point -> loads can't sink).
#pragma unroll
    for (int qi = 0; qi < 3; ++qi)
#pragma unroll
        for (int j = 0; j < 4; ++j) {
            if (BFX) {
                asm volatile("" :: "v"(xv[qi][j]));
            } else {
                asm volatile("" :: "v"(xf[qi][j][0]));
                asm volatile("" :: "v"(xf[qi][j][1]));
            }
        }

    // tr-read per-lane base addresses (addr = base + lane*8)
    const unsigned ldsb = (unsigned)(size_t)(&lds[0]);
    const unsigned xnb  = ldsb + (unsigned)(wv * 4224 + lane * 8);
    const unsigned wtb  = ldsb + 16896u + (unsigned)(wv * 4096 + lane * 8);

    // ---- Stage 1: barrier-free per-wave loop over own 4 queries ----
    float4v frag[4][4];
#pragma unroll
    for (int qi = 0; qi < 4; ++qi)
#pragma unroll
        for (int v = 0; v < 4; ++v) frag[qi][v] = (float4v){0.f, 0.f, 0.f, 0.f};

    // xn write base (shorts): v-stride 528 (=1056B) -> write phase's 8
    // 16B slots land on all 32 banks ({0,16,32,48,64,80,96,112} mod 128).
    const int Eb = (m8 >> 1) * 528 + ((q8 >> 2) & 1) * 256 + (q8 & 3) * 16 + (m8 & 1) * 8;

#pragma unroll
    for (int qi = 0; qi < 4; ++qi) {
        // write prefetched rows into tr layout
#pragma unroll
        for (int j = 0; j < 4; ++j) {
            short8 pv;
            if (BFX) {
                pv = xv[qi][j];
            } else {
                const float4v a0 = xf[qi][j][0], a1 = xf[qi][j][1];
                pv[0] = (short)f2bf(a0[0]); pv[1] = (short)f2bf(a0[1]);
                pv[2] = (short)f2bf(a0[2]); pv[3] = (short)f2bf(a0[3]);
                pv[4] = (short)f2bf(a1[0]); pv[5] = (short)f2bf(a1[1]);
                pv[6] = (short)f2bf(a1[2]); pv[7] = (short)f2bf(a1[3]);
            }
            *(short8*)&xn_own[Eb + j * 64] = pv;
        }
        __builtin_amdgcn_sched_barrier(0);   // pin stores before asm reads

        short4v a0, a1, b0[4], b1[4];
        asm volatile("ds_read_b64_tr_b16 %0, %1 offset:%c2"
                     : "=v"(a0) : "v"(wtb), "i"(qi * 1024) : "memory");
        asm volatile("ds_read_b64_tr_b16 %0, %1 offset:%c2"
                     : "=v"(a1) : "v"(wtb), "i"(qi * 1024 + 512) : "memory");
#pragma unroll
        for (int v = 0; v < 4; ++v) {
            asm volatile("ds_read_b64_tr_b16 %0, %1 offset:%c2"
                         : "=v"(b0[v]) : "v"(xnb), "i"(v * 1056) : "memory");
            asm volatile("ds_read_b64_tr_b16 %0, %1 offset:%c2"
                         : "=v"(b1[v]) : "v"(xnb), "i"(v * 1056 + 512) : "memory");
        }
        asm volatile("s_waitcnt lgkmcnt(0)");
        __builtin_amdgcn_sched_barrier(0);   // rule #18: no MFMA hoist past the wait

        short8 a;
#pragma unroll
        for (int e = 0; e < 4; ++e) { a[e] = a0[e]; a[e + 4] = a1[e]; }
#pragma unroll
        for (int v = 0; v < 4; ++v) {
            short8 bb;
#pragma unroll
            for (int e = 0; e < 4; ++e) { bb[e] = b0[v][e]; bb[e + 4] = b1[v][e]; }
            frag[qi][v] = __builtin_amdgcn_mfma_f32_16x16x32_bf16(a, bb, frag[qi][v], 0, 0, 0);
        }
    }

    __syncthreads();   // all waves done with xn/wT2 before Awt overwrites

    // ---- Round trip: C-frags -> Awt, k' = f*16 + kq, b64 writes ----
    // swz(B,q) = B ^ ((q&7)<<4) ^ (((B>>7)&3)<<4)  (bits>=4 only; involution)
    // write phase: 2-way (free); read phase: conflict-free b128.
    char* AwtB = (char*)lds;
#pragma unroll
    for (int qi = 0; qi < 4; ++qi) {
        const int qg = wv * 4 + qi;
        char* qb = AwtB + qg * 2048;
        const int xr = (qg & 7) << 4;
#pragma unroll
        for (int v = 0; v < 4; ++v) {
            short4v w;
#pragma unroll
            for (int r = 0; r < 4; ++r) w[r] = (short)f2bf(frag[qi][v][r]);
            const int Bw = (v * 16 + ml) * 32 + quad * 8;
            const int sw = Bw ^ xr ^ (((Bw >> 7) & 3) << 4);
            *(short4v*)(qb + sw) = w;
        }
    }
    __syncthreads();

    // ---- Stage 2: out[q][o] = sum_{k'} Awt[q][k'] * W'[k'][o], K'=1024 ----
    // One conflict-free b128 A-read per MFMA; even/odd accumulators.
    float4v acc0 = (float4v){0.f, 0.f, 0.f, 0.f};
    float4v acc1 = (float4v){0.f, 0.f, 0.f, 0.f};
    const short* bptr = Bfrag + (wv * 32) * 512 + lane * 8;
    const char*  arow = AwtB + ml * 2048;
    const int    xr2  = (ml & 7) << 4;
#pragma unroll 2
    for (int t = 0; t < 32; t += 2) {
        {
            const int B0 = t * 64 + quad * 16;
            const int ad = B0 ^ xr2 ^ ((((unsigned)B0 >> 7) & 3) << 4);
            const short8 a = *(const short8*)(arow + ad);
            const short8 bb = *(const short8*)(bptr + t * 512);
            acc0 = __builtin_amdgcn_mfma_f32_16x16x32_bf16(a, bb, acc0, 0, 0, 0);
        }
        {
            const int t1 = t + 1;
            const int B0 = t1 * 64 + quad * 16;
            const int ad = B0 ^ xr2 ^ ((((unsigned)B0 >> 7) & 3) << 4);
            const short8 a = *(const short8*)(arow + ad);
            const short8 bb = *(const short8*)(bptr + t1 * 512);
            acc1 = __builtin_amdgcn_mfma_f32_16x16x32_bf16(a, bb, acc1, 0, 0, 0);
        }
    }
    const float4v acc = acc0 + acc1;

    // ---- Epilogue: write raw out + per-block channel sums (BN partials) ----
    float s = 0.f, s2 = 0.f;
#pragma unroll
    for (int r = 0; r < 4; ++r) {
        const float v = acc[r];
        out_raw[(q0 + quad * 4 + r) * OUTC + wv * 16 + ml] = v;
        s += v; s2 += v * v;
    }
    s  += __shfl_xor(s, 16, 64);  s  += __shfl_xor(s, 32, 64);
    s2 += __shfl_xor(s2, 16, 64); s2 += __shfl_xor(s2, 32, 64);
    if (quad == 0) {
        const int c = wv * 16 + ml;
        psum[c * 4096 + blockIdx.x]          = s;
        psum[262144 + c * 4096 + blockIdx.x] = s2;
    }
}

// ---------------------------------------------------------------------------
// BN stats: one block per channel, reduce 4096 partials -> scale/shift
// ---------------------------------------------------------------------------
__global__ __launch_bounds__(256) void bn_stats(
    const float* __restrict__ psum, const float* __restrict__ gamma,
    const float* __restrict__ beta, float* __restrict__ sc_sh)
{
    const int c = blockIdx.x;
    const int t = threadIdx.x;
    float s = 0.f, q = 0.f;
#pragma unroll
    for (int i = 0; i < 16; ++i) {
        s += psum[c * 4096 + t + i * 256];
        q += psum[262144 + c * 4096 + t + i * 256];
    }
    __shared__ float rs[4], rq[4];
#pragma unroll
    for (int off = 32; off; off >>= 1) {
        s += __shfl_down(s, off, 64);
        q += __shfl_down(q, off, 64);
    }
    if ((t & 63) == 0) { rs[t >> 6] = s; rq[t >> 6] = q; }
    __syncthreads();
    if (t == 0) {
        s = rs[0] + rs[1] + rs[2] + rs[3];
        q = rq[0] + rq[1] + rq[2] + rq[3];
        const float mean = s * (1.0f / (float)NQ);
        const float var  = q * (1.0f / (float)NQ) - mean * mean;
        const float scale = gamma[c] / sqrtf(var + 1e-5f);
        sc_sh[c]      = scale;
        sc_sh[64 + c] = beta[c] - mean * scale;
    }
}

// ---------------------------------------------------------------------------
// Apply BN + LeakyReLU(0.1) in place (float4)
// ---------------------------------------------------------------------------
__global__ __launch_bounds__(256) void bn_apply(
    float* __restrict__ out, const float* __restrict__ sc_sh)
{
    __shared__ float sc[64];
    __shared__ float sh[64];
    if (threadIdx.x < 64) {
        sc[threadIdx.x] = sc_sh[threadIdx.x];
        sh[threadIdx.x] = sc_sh[64 + threadIdx.x];
    }
    __syncthreads();
    const int idx = blockIdx.x * 256 + threadIdx.x;
#pragma unroll
    for (int it = 0; it < 4; ++it) {
        const int e = idx + it * 262144;
        float4 v = ((const float4*)out)[e];
        const int cg = (e & 15) * 4;
        float4 r;
        r.x = v.x * sc[cg + 0] + sh[cg + 0];
        r.y = v.y * sc[cg + 1] + sh[cg + 1];
        r.z = v.z * sc[cg + 2] + sh[cg + 2];
        r.w = v.w * sc[cg + 3] + sh[cg + 3];
        r.x = r.x >= 0.0f ? r.x : 0.1f * r.x;
        r.y = r.y >= 0.0f ? r.y : 0.1f * r.y;
        r.z = r.z >= 0.0f ? r.z : 0.1f * r.z;
        r.w = r.w >= 0.0f ? r.w : 0.1f * r.w;
        ((float4*)out)[e] = r;
    }
}

// ---------------------------------------------------------------------------
extern "C" void kernel_launch(void* const* d_in, const int* in_sizes, int n_in,
                              void* d_out, int out_size, void* d_ws, size_t ws_size,
                              hipStream_t stream)
{
    (void)in_sizes; (void)n_in; (void)out_size;
    const float* x     = (const float*)d_in[0];
    const float* qp    = (const float*)d_in[1];
    const float* sp    = (const float*)d_in[2];
    const int*   inds  = (const int*)d_in[3];
    const float* kp    = (const float*)d_in[4];
    const float* W     = (const float*)d_in[5];
    const float* gamma = (const float*)d_in[6];
    const float* beta  = (const float*)d_in[7];
    float* out = (float*)d_out;

    short*          Bfrag = (short*)d_ws;
    float*          psum  = (float*)((char*)d_ws + OFF_PSUM);
    float*          sc_sh = (float*)((char*)d_ws + OFF_SCSH);
    unsigned short* xbf   = (unsigned short*)((char*)d_ws + OFF_XBF);

    const int use_bf = (ws_size >= NEED_BF16) ? 1 : 0;

    prep_all<<<4352, 256, 0, stream>>>(W, x, Bfrag, xbf, use_bf);
    if (use_bf)
        kpconv_mfma<true><<<NQ / QB, 256, 0, stream>>>(x, xbf, qp, sp, inds, kp, Bfrag, out, psum);
    else
        kpconv_mfma<false><<<NQ / QB, 256, 0, stream>>>(x, xbf, qp, sp, inds, kp, Bfrag, out, psum);
    bn_stats<<<64, 256, 0, stream>>>(psum, gamma, beta, sc_sh);
    bn_apply<<<1024, 256, 0, stream>>>(out, sc_sh);
}

// Round 10
// 143.815 us; speedup vs baseline: 2.5465x; 1.0199x over previous
//
#include <hip/hip_runtime.h>
#include <math.h>

// Problem constants
#define NQ   65536
#define H    32
#define IN   64
#define OUTC 64
#define K    15
#define QB   16          // queries per block
#define INV_EXT (1.0f / 0.048f)

// d_ws layout (bytes)
#define OFF_PSUM  131072                       // Bfrag region: 65536 shorts = 128 KB exact
#define OFF_SCSH  (OFF_PSUM + 2097152)         // 128 floats
#define OFF_XBF   (OFF_SCSH + 1024)            // x in bf16: 8 MB
#define NEED_BF16 (OFF_XBF + (size_t)NQ * IN * 2)

typedef __attribute__((ext_vector_type(8))) short short8;
typedef __attribute__((ext_vector_type(4))) short short4v;
typedef __attribute__((ext_vector_type(4))) float float4v;

static __device__ __forceinline__ unsigned short f2bf(float f) {
    return (unsigned short)((__float_as_uint(f) + 0x8000u) >> 16);
}
static __device__ __forceinline__ unsigned pk2(float a, float b) {
    return (__float_as_uint(a) + 0x8000u) >> 16 |
           ((__float_as_uint(b) + 0x8000u) & 0xFFFF0000u);
}

// ---------------------------------------------------------------------------
// Prep: blocks [0,4096): x fp32 -> bf16 (coalesced).
//       blocks [4096,4352): W repack -> stage-2 B-frag dump order with
//       k' = i*16 + kq (kq==15 is a zero row; K'=1024, 32 MFMA steps).
// ---------------------------------------------------------------------------
__global__ __launch_bounds__(256) void prep_all(
    const float* __restrict__ W, const float* __restrict__ x,
    short* __restrict__ Bfrag, unsigned short* __restrict__ xbf, int do_x)
{
    const int b = blockIdx.x;
    if (b < 4096) {
        if (do_x) {
            const int t = b * 256 + threadIdx.x;      // float4 index
            const float4 v = ((const float4*)x)[t];
            uint2 p; p.x = pk2(v.x, v.y); p.y = pk2(v.z, v.w);
            ((uint2*)xbf)[t] = p;
        }
    } else {
        const int t2  = (b - 4096) * 256 + threadIdx.x;   // 0..65535
        const int j   = t2 & 7;
        const int ln  = (t2 >> 3) & 63;
        const int tt  = (t2 >> 9) & 31;
        const int wvq = t2 >> 14;
        const int kp2 = tt * 32 + (ln >> 4) * 8 + j;      // k' = i*16 + kq
        const int kq  = kp2 & 15;
        const int ii  = kp2 >> 4;
        const int oo  = wvq * 16 + (ln & 15);
        const float val = (kq < K) ? W[(kq * 64 + ii) * 64 + oo] : 0.0f;
        Bfrag[t2] = (short)f2bf(val);
    }
}

// ---------------------------------------------------------------------------
// Main kernel. R23 = R9 (legal, verified, 60 us) + two ISA-level latency fixes
// (the two largest measured serial exposures per wave):
//  (1) GATHERS AS ORDERED ASM: VGPR=52 proved the compiler sank the 16
//      prefetched gathers into the qi loop (asm "pins" can move vs normal
//      code; asm OUTPUTS cannot). 16x global_load_dwordx4 issued as one
//      batch AFTER stage A (so compiler waitcnts for sp/qp can't drain
//      ours), consumed with counted s_waitcnt vmcnt(12/8/4/0) per qi +
//      sched_barrier fences. Exposure ~2160 -> ~870 cyc/wave.
//  (2) STAGE-2 RING-8: 32 independent L2 Bfrag loads were consumed at
//      pipeline depth 2 (~3000 cyc exposed). Ring of 8 short8 registers,
//      full unroll (static indices, rule #20): load t+8 at use of t ->
//      ~200 cyc of work per load in flight, covering ~250 cyc L2 latency.
// LDS phase1: xn 4x4224B=16896 + wT2 16384B = 33280B. Phase2: Awt 32768B.
// 4 blocks/CU; launch_bounds(256,4) -> 128-VGPR budget for the pipelines.
// ---------------------------------------------------------------------------
template<bool BFX>
__global__ __launch_bounds__(256, 4) void kpconv_mfma(
    const float* __restrict__ x, const unsigned short* __restrict__ xbf,
    const float* __restrict__ qp, const float* __restrict__ sp,
    const int* __restrict__ inds, const float* __restrict__ kp,
    const short* __restrict__ Bfrag, float* __restrict__ out_raw,
    float* __restrict__ psum)
{
    __shared__ __align__(16) short lds[16640];            // 33280 B, all in bounds
    short* xn  = lds;                                     // 4 waves x 2112 shorts (1056B v-stride)
    short* wT2 = lds + 8448;                              // [16 qg][512] tr-layout

    const int tid  = threadIdx.x;
    const int lane = tid & 63;
    const int wv   = tid >> 6;
    const int quad = lane >> 4;
    const int ml   = lane & 15;
    const int q8   = lane >> 3;                           // neighbor slot 0..7 (contiguous lanes)
    const int m8   = lane & 7;                            // feat octet 0..7
    const int q0   = blockIdx.x * QB;

    short* xn_own = xn + wv * 2112;                       // wave-private tr buffer (4224 B)

    // ---- Load all 16 gather indices early (latency hides under stage A) ----
    int id16[4][4];
#pragma unroll
    for (int qi = 0; qi < 4; ++qi) {
        const int ibase = (q0 + wv * 4 + qi) * H;
#pragma unroll
        for (int j = 0; j < 4; ++j)
            id16[qi][j] = inds[ibase + j * 8 + q8];
    }

    // ---- Stage A: influence weights -> wT2 tr-layout (2 x b128 per lane/rep)
    // wT2 elem(qg,h,kq) = qg*512 + ((h>>2)&1)*256 + (h>>3)*64 + (h&3)*16 + kq
#pragma unroll
    for (int rep = 0; rep < 2; ++rep) {
        const int p  = lane + rep * 64;      // 0..127
        const int qi = p >> 5, h = p & 31;
        const int qg = wv * 4 + qi;
        const int n  = q0 + qg;
        const int id = inds[n * H + h];
        const float dx = sp[id * 3 + 0] - qp[n * 3 + 0];
        const float dy = sp[id * 3 + 1] - qp[n * 3 + 1];
        const float dz = sp[id * 3 + 2] - qp[n * 3 + 2];
        short8 w0, w1;
#pragma unroll
        for (int k = 0; k < K; ++k) {
            const float ex = dx - kp[k * 3 + 0];
            const float ey = dy - kp[k * 3 + 1];
            const float ez = dz - kp[k * 3 + 2];
            const float sq = ex * ex + ey * ey + ez * ez;
            float wval = 1.0f - __builtin_amdgcn_sqrtf(sq) * INV_EXT;
            wval = wval > 0.0f ? wval : 0.0f;
            if (k < 8) w0[k]     = (short)f2bf(wval);
            else       w1[k - 8] = (short)f2bf(wval);
        }
        w1[7] = 0;                           // kq = 15 zero column
        short* dst = wT2 + qg * 512 + ((h >> 2) & 1) * 256 + (h >> 3) * 64 + (h & 3) * 16;
        *(short8*)dst       = w0;
        *(short8*)(dst + 8) = w1;
    }
    // no barrier: wT2 rows qg in [4wv,4wv+4) are read only by this wave

    // ---- Issue ALL 16 gathers as ORDERED asm loads (cannot sink) ----
    short8 xg[4][4];
    if (BFX) {
        __builtin_amdgcn_sched_barrier(0);   // stage-A code may not sink below
#pragma unroll
        for (int qi = 0; qi < 4; ++qi)
#pragma unroll
            for (int j = 0; j < 4; ++j) {
                const char* ga = (const char*)xbf +
                                 ((size_t)(unsigned)id16[qi][j] * 128) + m8 * 16;
                asm volatile("global_load_dwordx4 %0, %1, off"
                             : "=v"(xg[qi][j]) : "v"(ga));
            }
    }

    // tr-read per-lane base addresses (addr = base + lane*8)
    const unsigned ldsb = (unsigned)(size_t)(&lds[0]);
    const unsigned xnb  = ldsb + (unsigned)(wv * 4224 + lane * 8);
    const unsigned wtb  = ldsb + 16896u + (unsigned)(wv * 4096 + lane * 8);

    // ---- Stage 1: barrier-free per-wave loop over own 4 queries ----
    float4v frag[4][4];
#pragma unroll
    for (int qi = 0; qi < 4; ++qi)
#pragma unroll
        for (int v = 0; v < 4; ++v) frag[qi][v] = (float4v){0.f, 0.f, 0.f, 0.f};

    // xn write base (shorts): v-stride 528 (=1056B) -> write phase's 8
    // 16B slots land on all 32 banks ({0,16,32,...,112} mod 128).
    const int Eb = (m8 >> 1) * 528 + ((q8 >> 2) & 1) * 256 + (q8 & 3) * 16 + (m8 & 1) * 8;

#pragma unroll
    for (int qi = 0; qi < 4; ++qi) {
        if (BFX) {
            // wait for THIS qi's 4 loads only (counted; loads retire in order)
            if      (qi == 0) asm volatile("s_waitcnt vmcnt(12)");
            else if (qi == 1) asm volatile("s_waitcnt vmcnt(8)");
            else if (qi == 2) asm volatile("s_waitcnt vmcnt(4)");
            else              asm volatile("s_waitcnt vmcnt(0)");
            __builtin_amdgcn_sched_barrier(0);   // stores may not hoist above wait
#pragma unroll
            for (int j = 0; j < 4; ++j)
                *(short8*)&xn_own[Eb + j * 64] = xg[qi][j];
        } else {
            const int ibase = (q0 + wv * 4 + qi) * H;
#pragma unroll
            for (int j = 0; j < 4; ++j) {
                const int id = id16[qi][j]; (void)ibase;
                const float4v a0 = *(const float4v*)(x + id * IN + m8 * 8);
                const float4v a1 = *(const float4v*)(x + id * IN + m8 * 8 + 4);
                short8 pv;
                pv[0] = (short)f2bf(a0[0]); pv[1] = (short)f2bf(a0[1]);
                pv[2] = (short)f2bf(a0[2]); pv[3] = (short)f2bf(a0[3]);
                pv[4] = (short)f2bf(a1[0]); pv[5] = (short)f2bf(a1[1]);
                pv[6] = (short)f2bf(a1[2]); pv[7] = (short)f2bf(a1[3]);
                *(short8*)&xn_own[Eb + j * 64] = pv;
            }
        }
        __builtin_amdgcn_sched_barrier(0);   // pin stores before asm tr reads

        short4v a0, a1, b0[4], b1[4];
        asm volatile("ds_read_b64_tr_b16 %0, %1 offset:%c2"
                     : "=v"(a0) : "v"(wtb), "i"(qi * 1024) : "memory");
        asm volatile("ds_read_b64_tr_b16 %0, %1 offset:%c2"
                     : "=v"(a1) : "v"(wtb), "i"(qi * 1024 + 512) : "memory");
#pragma unroll
        for (int v = 0; v < 4; ++v) {
            asm volatile("ds_read_b64_tr_b16 %0, %1 offset:%c2"
                         : "=v"(b0[v]) : "v"(xnb), "i"(v * 1056) : "memory");
            asm volatile("ds_read_b64_tr_b16 %0, %1 offset:%c2"
                         : "=v"(b1[v]) : "v"(xnb), "i"(v * 1056 + 512) : "memory");
        }
        asm volatile("s_waitcnt lgkmcnt(0)");
        __builtin_amdgcn_sched_barrier(0);   // rule #18: no MFMA hoist past the wait

        short8 a;
#pragma unroll
        for (int e = 0; e < 4; ++e) { a[e] = a0[e]; a[e + 4] = a1[e]; }
#pragma unroll
        for (int v = 0; v < 4; ++v) {
            short8 bb;
#pragma unroll
            for (int e = 0; e < 4; ++e) { bb[e] = b0[v][e]; bb[e + 4] = b1[v][e]; }
            frag[qi][v] = __builtin_amdgcn_mfma_f32_16x16x32_bf16(a, bb, frag[qi][v], 0, 0, 0);
        }
    }

    __syncthreads();   // all waves done with xn/wT2 before Awt overwrites

    // ---- Round trip: C-frags -> Awt, k' = f*16 + kq, b64 writes ----
    // swz(B,q) = B ^ ((q&7)<<4) ^ (((B>>7)&3)<<4)  (bits>=4 only; involution)
    // write phase: 2-way (free); read phase: conflict-free b128.
    char* AwtB = (char*)lds;
#pragma unroll
    for (int qi = 0; qi < 4; ++qi) {
        const int qg = wv * 4 + qi;
        char* qb = AwtB + qg * 2048;
        const int xr = (qg & 7) << 4;
#pragma unroll
        for (int v = 0; v < 4; ++v) {
            short4v w;
#pragma unroll
            for (int r = 0; r < 4; ++r) w[r] = (short)f2bf(frag[qi][v][r]);
            const int Bw = (v * 16 + ml) * 32 + quad * 8;
            const int sw = Bw ^ xr ^ (((Bw >> 7) & 3) << 4);
            *(short4v*)(qb + sw) = w;
        }
    }
    __syncthreads();

    // ---- Stage 2: out[q][o] = sum_{k'} Awt[q][k'] * W'[k'][o], K'=1024 ----
    // Ring-8 register prefetch of the 32 L2-resident Bfrag loads; one
    // conflict-free b128 A-read per MFMA; even/odd accumulators.
    float4v acc0 = (float4v){0.f, 0.f, 0.f, 0.f};
    float4v acc1 = (float4v){0.f, 0.f, 0.f, 0.f};
    const short* bptr = Bfrag + (wv * 32) * 512 + lane * 8;
    const char*  arow = AwtB + ml * 2048;
    const int    xr2  = (ml & 7) << 4;

    short8 breg[8];
#pragma unroll
    for (int t = 0; t < 8; ++t) breg[t] = *(const short8*)(bptr + t * 512);

#pragma unroll
    for (int t = 0; t < 32; ++t) {
        const short8 bb = breg[t & 7];
        if (t < 24) breg[t & 7] = *(const short8*)(bptr + (t + 8) * 512);
        const int B0 = t * 64 + quad * 16;
        const int ad = B0 ^ xr2 ^ ((((unsigned)B0 >> 7) & 3) << 4);
        const short8 a = *(const short8*)(arow + ad);
        if (t & 1) acc1 = __builtin_amdgcn_mfma_f32_16x16x32_bf16(a, bb, acc1, 0, 0, 0);
        else       acc0 = __builtin_amdgcn_mfma_f32_16x16x32_bf16(a, bb, acc0, 0, 0, 0);
    }
    const float4v acc = acc0 + acc1;

    // ---- Epilogue: write raw out + per-block channel sums (BN partials) ----
    float s = 0.f, s2 = 0.f;
#pragma unroll
    for (int r = 0; r < 4; ++r) {
        const float v = acc[r];
        out_raw[(q0 + quad * 4 + r) * OUTC + wv * 16 + ml] = v;
        s += v; s2 += v * v;
    }
    s  += __shfl_xor(s, 16, 64);  s  += __shfl_xor(s, 32, 64);
    s2 += __shfl_xor(s2, 16, 64); s2 += __shfl_xor(s2, 32, 64);
    if (quad == 0) {
        const int c = wv * 16 + ml;
        psum[c * 4096 + blockIdx.x]          = s;
        psum[262144 + c * 4096 + blockIdx.x] = s2;
    }
}

// ---------------------------------------------------------------------------
// BN stats: one block per channel, reduce 4096 partials -> scale/shift
// ---------------------------------------------------------------------------
__global__ __launch_bounds__(256) void bn_stats(
    const float* __restrict__ psum, const float* __restrict__ gamma,
    const float* __restrict__ beta, float* __restrict__ sc_sh)
{
    const int c = blockIdx.x;
    const int t = threadIdx.x;
    float s = 0.f, q = 0.f;
#pragma unroll
    for (int i = 0; i < 16; ++i) {
        s += psum[c * 4096 + t + i * 256];
        q += psum[262144 + c * 4096 + t + i * 256];
    }
    __shared__ float rs[4], rq[4];
#pragma unroll
    for (int off = 32; off; off >>= 1) {
        s += __shfl_down(s, off, 64);
        q += __shfl_down(q, off, 64);
    }
    if ((t & 63) == 0) { rs[t >> 6] = s; rq[t >> 6] = q; }
    __syncthreads();
    if (t == 0) {
        s = rs[0] + rs[1] + rs[2] + rs[3];
        q = rq[0] + rq[1] + rq[2] + rq[3];
        const float mean = s * (1.0f / (float)NQ);
        const float var  = q * (1.0f / (float)NQ) - mean * mean;
        const float scale = gamma[c] / sqrtf(var + 1e-5f);
        sc_sh[c]      = scale;
        sc_sh[64 + c] = beta[c] - mean * scale;
    }
}

// ---------------------------------------------------------------------------
// Apply BN + LeakyReLU(0.1) in place (float4)
// ---------------------------------------------------------------------------
__global__ __launch_bounds__(256) void bn_apply(
    float* __restrict__ out, const float* __restrict__ sc_sh)
{
    __shared__ float sc[64];
    __shared__ float sh[64];
    if (threadIdx.x < 64) {
        sc[threadIdx.x] = sc_sh[threadIdx.x];
        sh[threadIdx.x] = sc_sh[64 + threadIdx.x];
    }
    __syncthreads();
    const int idx = blockIdx.x * 256 + threadIdx.x;
#pragma unroll
    for (int it = 0; it < 4; ++it) {
        const int e = idx + it * 262144;
        float4 v = ((const float4*)out)[e];
        const int cg = (e & 15) * 4;
        float4 r;
        r.x = v.x * sc[cg + 0] + sh[cg + 0];
        r.y = v.y * sc[cg + 1] + sh[cg + 1];
        r.z = v.z * sc[cg + 2] + sh[cg + 2];
        r.w = v.w * sc[cg + 3] + sh[cg + 3];
        r.x = r.x >= 0.0f ? r.x : 0.1f * r.x;
        r.y = r.y >= 0.0f ? r.y : 0.1f * r.y;
        r.z = r.z >= 0.0f ? r.z : 0.1f * r.z;
        r.w = r.w >= 0.0f ? r.w : 0.1f * r.w;
        ((float4*)out)[e] = r;
    }
}

// ---------------------------------------------------------------------------
extern "C" void kernel_launch(void* const* d_in, const int* in_sizes, int n_in,
                              void* d_out, int out_size, void* d_ws, size_t ws_size,
                              hipStream_t stream)
{
    (void)in_sizes; (void)n_in; (void)out_size;
    const float* x     = (const float*)d_in[0];
    const float* qp    = (const float*)d_in[1];
    const float* sp    = (const float*)d_in[2];
    const int*   inds  = (const int*)d_in[3];
    const float* kp    = (const float*)d_in[4];
    const float* W     = (const float*)d_in[5];
    const float* gamma = (const float*)d_in[6];
    const float* beta  = (const float*)d_in[7];
    float* out = (float*)d_out;

    short*          Bfrag = (short*)d_ws;
    float*          psum  = (float*)((char*)d_ws + OFF_PSUM);
    float*          sc_sh = (float*)((char*)d_ws + OFF_SCSH);
    unsigned short* xbf   = (unsigned short*)((char*)d_ws + OFF_XBF);

    const int use_bf = (ws_size >= NEED_BF16) ? 1 : 0;

    prep_all<<<4352, 256, 0, stream>>>(W, x, Bfrag, xbf, use_bf);
    if (use_bf)
        kpconv_mfma<true><<<NQ / QB, 256, 0, stream>>>(x, xbf, qp, sp, inds, kp, Bfrag, out, psum);
    else
        kpconv_mfma<false><<<NQ / QB, 256, 0, stream>>>(x, xbf, qp, sp, inds, kp, Bfrag, out, psum);
    bn_stats<<<64, 256, 0, stream>>>(psum, gamma, beta, sc_sh);
    bn_apply<<<1024, 256, 0, stream>>>(out, sc_sh);
}